// Round 5
// baseline (369.837 us; speedup 1.0000x reference)
//
#include <hip/hip_runtime.h>
#include <stdint.h>

typedef unsigned short u16;
typedef __attribute__((ext_vector_type(8))) short short8;
typedef __attribute__((ext_vector_type(4))) float floatx4;

#define MFMA_BF16 __builtin_amdgcn_mfma_f32_16x16x32_bf16

// dims
#define BB 4
#define TT 2048
#define CC 1024
#define HH 16
#define DH 64
#define MM (BB * TT)      // 8192
#define NQKV (3 * CC)     // 3072

// fixed softmax offset: 16 (e-domain) * log2(e), in exp2 domain
#define SOFTMAX_OFF 23.083120654223414f

__device__ __forceinline__ u16 f2bf(float f) {
  union { float f; uint32_t u; } un;
  un.f = f;
  uint32_t u = un.u;
  u += 0x7fffu + ((u >> 16) & 1u);   // round-to-nearest-even
  return (u16)(u >> 16);
}

__device__ __forceinline__ uint32_t pk2(float a, float b) {
  return (uint32_t)f2bf(a) | ((uint32_t)f2bf(b) << 16);
}

// async global->LDS, 16B per lane. lds dst = wave-uniform base + lane*16.
__device__ __forceinline__ void gload_lds16(const u16* g, u16* l) {
  __builtin_amdgcn_global_load_lds(
      (const __attribute__((address_space(1))) unsigned int*)g,
      (__attribute__((address_space(3))) unsigned int*)l, 16, 0, 0);
}

// ---------------------------------------------------------------------------
// Kernel 0: fp32 -> bf16 conversions + coalesced weight transpose.
//   blocks [0,8192):      x -> xb, float4 vectorized (4 elems/thread)
//   blocks [8192,11264):  W{q,k,v} [h][c][d] -> Wt[sec*1024+h*64+d][c]
//                         via 32x32 LDS tile transpose (both sides coalesced)
//   blocks [11264,12288): Wo -> Wob, float4 vectorized
// ---------------------------------------------------------------------------
__global__ __launch_bounds__(256) void convert_kernel(
    const float* __restrict__ x, const float* __restrict__ Wq,
    const float* __restrict__ Wk, const float* __restrict__ Wv,
    const float* __restrict__ Wo, u16* __restrict__ xb,
    u16* __restrict__ Wt, u16* __restrict__ Wob) {
  __shared__ float T[32][33];
  int bid = blockIdx.x, tid = threadIdx.x;
  if (bid < 8192) {
    int i = (bid * 256 + tid) * 4;
    float4 f = *(const float4*)(x + i);
    uint2 o = {pk2(f.x, f.y), pk2(f.z, f.w)};
    *(uint2*)(xb + i) = o;
  } else if (bid < 8192 + 3072) {
    int tb = bid - 8192;
    int sec = tb >> 10, rem = tb & 1023;
    int h = rem >> 6, sub = rem & 63, ct = sub >> 1, dt = sub & 1;
    const float* W = (sec == 0) ? Wq : (sec == 1) ? Wk : Wv;
    int tx = tid & 31, ty = tid >> 5;
#pragma unroll
    for (int p = 0; p < 4; ++p)
      T[ty + 8 * p][tx] =
          W[((size_t)h * CC + ct * 32 + ty + 8 * p) * DH + dt * 32 + tx];
    __syncthreads();
#pragma unroll
    for (int p = 0; p < 4; ++p) {
      int n = sec * 1024 + h * 64 + dt * 32 + ty + 8 * p;
      Wt[(size_t)n * CC + ct * 32 + tx] = f2bf(T[tx][ty + 8 * p]);
    }
  } else {
    int i = ((bid - 11264) * 256 + tid) * 4;
    float4 f = *(const float4*)(Wo + i);
    uint2 o = {pk2(f.x, f.y), pk2(f.z, f.w)};
    *(uint2*)(Wob + i) = o;
  }
}

// ---------------------------------------------------------------------------
// GEMM: C[M,N] = A[M,K] @ Bt[N,K]^T, bf16 in, fp32 accum. m97 pattern.
// ---------------------------------------------------------------------------
template <int MODE>
__global__ __launch_bounds__(256) void gemm_bt(
    const u16* __restrict__ A, const u16* __restrict__ Bt, int M, int N, int K,
    u16* __restrict__ qout, u16* __restrict__ kout, u16* __restrict__ vtout,
    float* __restrict__ out, const float* __restrict__ bias) {
  __shared__ u16 As[128][64];  // unpadded: required by global_load_lds
  __shared__ u16 Bs[128][64];
  int tid = threadIdx.x;
  int lane = tid & 63, w = tid >> 6;
  int wm = w >> 1, wn = w & 1;
  int g = lane >> 4, c = lane & 15;
  int m0 = blockIdx.y * 128, n0 = blockIdx.x * 128;

  floatx4 acc[4][4];
#pragma unroll
  for (int i = 0; i < 4; ++i)
#pragma unroll
    for (int j = 0; j < 4; ++j) acc[i][j] = (floatx4){0.f, 0.f, 0.f, 0.f};

  int srow = 32 * w + (lane >> 3);
  int scol = (lane & 7) * 8;
  const u16* Ag = A + (size_t)(m0 + srow) * K + scol;
  const u16* Bg = Bt + (size_t)(n0 + srow) * K + scol;
  u16* AsB = &As[32 * w][0];
  u16* BsB = &Bs[32 * w][0];

  for (int k0 = 0; k0 < K; k0 += 64) {
    __syncthreads();
#pragma unroll
    for (int j = 0; j < 4; ++j)
      gload_lds16(Ag + k0 + (size_t)j * 8 * K, AsB + j * 512);
#pragma unroll
    for (int j = 0; j < 4; ++j)
      gload_lds16(Bg + k0 + (size_t)j * 8 * K, BsB + j * 512);
    __syncthreads();
#pragma unroll
    for (int kc = 0; kc < 2; ++kc) {
      short8 af[4], bfv[4];
#pragma unroll
      for (int mt = 0; mt < 4; ++mt)
        af[mt] = *(const short8*)(&As[wm * 64 + mt * 16 + c][kc * 32 + g * 8]);
#pragma unroll
      for (int nt = 0; nt < 4; ++nt)
        bfv[nt] = *(const short8*)(&Bs[wn * 64 + nt * 16 + c][kc * 32 + g * 8]);
#pragma unroll
      for (int mt = 0; mt < 4; ++mt)
#pragma unroll
        for (int nt = 0; nt < 4; ++nt)
          acc[mt][nt] = MFMA_BF16(af[mt], bfv[nt], acc[mt][nt], 0, 0, 0);
    }
  }

#pragma unroll
  for (int mt = 0; mt < 4; ++mt) {
#pragma unroll
    for (int nt = 0; nt < 4; ++nt) {
#pragma unroll
      for (int r = 0; r < 4; ++r) {
        int m = m0 + wm * 64 + mt * 16 + g * 4 + r;  // C-layout: row=(lane>>4)*4+reg
        int n = n0 + wn * 64 + nt * 16 + c;          //           col=lane&15
        float v = acc[mt][nt][r];
        if (MODE == 0) {
          int b = m >> 11, t = m & 2047;
          int sec = n >> 10, h = (n >> 6) & 15, d = n & 63;
          size_t bh = (size_t)(b * HH + h);
          if (sec == 0)
            qout[(bh * TT + t) * DH + d] = f2bf(v * 0.18033688011112042f);
          // ^ DH^-0.5 * log2(e): softmax runs in exp2 domain
          else if (sec == 1)
            kout[(bh * TT + t) * DH + d] = f2bf(v);
          else
            vtout[(bh * DH + d) * TT + t] = f2bf(v);  // V^T for PV frags
        } else {
          out[(size_t)m * N + n] = v + bias[n];
        }
      }
    }
  }
}

// ---------------------------------------------------------------------------
// Flash attention (causal), fixed-max softmax. 256 thr = 4 waves; wave w owns
// Q rows [t0+32w, t0+32w+32). 64-key tiles. K fragments read DIRECT from
// global (L1/L2-hot, coalesced); only V + P transit LDS. Q re-read from L1
// each iter (saves 32 persistent VGPRs). Fully-masked wave-tiles skip compute.
// ---------------------------------------------------------------------------
__global__ __launch_bounds__(256, 4) void flash_attn(
    const u16* __restrict__ q, const u16* __restrict__ k,
    const u16* __restrict__ vT, u16* __restrict__ O) {
  __shared__ u16 Vs[64][72];     // [d][s]
  __shared__ u16 Ps[4][32][72];  // per-wave P tile [m 0..31][s]

  int tid = threadIdx.x;
  int lane = tid & 63, w = tid >> 6;
  int g = lane >> 4, c = lane & 15;

  // balance swizzle: alternate heavy/light direction per 256-block group
  int id = blockIdx.y * 16 + blockIdx.x;
  int bh = id >> 4;
  int x = id & 15;
  int t0 = (((id >> 8) & 1) ? x : 15 - x) * 128;

  const u16* qb = q + (size_t)bh * TT * DH + (size_t)(t0 + w * 32 + c) * DH;
  const u16* kb = k + (size_t)bh * TT * DH;
  const u16* vb = vT + (size_t)bh * DH * TT;

  floatx4 oacc[2][4];
#pragma unroll
  for (int mt = 0; mt < 2; ++mt)
#pragma unroll
    for (int nt = 0; nt < 4; ++nt) oacc[mt][nt] = (floatx4){0.f, 0.f, 0.f, 0.f};
  float lsum[2][4];
#pragma unroll
  for (int mt = 0; mt < 2; ++mt)
#pragma unroll
    for (int r = 0; r < 4; ++r) lsum[mt][r] = 0.f;

  // V staging: row = tid>>2 (0..63 d), col base = (tid&3)*16, 2x16B
  int srow = tid >> 2, scol = (tid & 3) * 16;
  const u16* vbase = vb + (size_t)srow * TT + scol;
  uint4 vr0 = *(const uint4*)(vbase);
  uint4 vr1 = *(const uint4*)(vbase + 8);

  int niter = (t0 >> 6) + 2;
  int nfull = t0 >> 6;  // iterations needing no causal mask
  int wmax = t0 + w * 32 + 31;
  for (int it = 0; it < niter; ++it) {
    int s0 = it << 6;
    __syncthreads();  // all waves done reading prev V tile
    *(uint4*)(&Vs[srow][scol]) = vr0;
    *(uint4*)(&Vs[srow][scol + 8]) = vr1;
    __syncthreads();
    if (it + 1 < niter) {  // prefetch next V tile
      int s1 = (it + 1) << 6;
      vr0 = *(const uint4*)(vbase + s1);
      vr1 = *(const uint4*)(vbase + s1 + 8);
    }
    if (s0 > wmax) continue;  // wave-uniform: tile fully masked (last iter)
    bool masked = (it >= nfull);
    const u16* kt = kb + (size_t)s0 * DH;

    // S = Q K^T ; K frags direct from global, shared across both m-tiles
    floatx4 z[2][4];
#pragma unroll
    for (int mt = 0; mt < 2; ++mt)
#pragma unroll
      for (int n = 0; n < 4; ++n) z[mt][n] = (floatx4){0.f, 0.f, 0.f, 0.f};
#pragma unroll
    for (int kc = 0; kc < 2; ++kc) {
      short8 qf0 = *(const short8*)(qb + kc * 32 + g * 8);
      short8 qf1 = *(const short8*)(qb + 16 * DH + kc * 32 + g * 8);
#pragma unroll
      for (int n = 0; n < 4; ++n) {
        short8 kf = *(const short8*)(kt + (size_t)(n * 16 + c) * DH + kc * 32 + g * 8);
        z[0][n] = MFMA_BF16(qf0, kf, z[0][n], 0, 0, 0);
        z[1][n] = MFMA_BF16(qf1, kf, z[1][n], 0, 0, 0);
      }
    }

    // fixed-max softmax, inlined per row; write P to per-wave LDS
#pragma unroll
    for (int mt = 0; mt < 2; ++mt) {
      int qr = t0 + w * 32 + mt * 16 + g * 4;
#pragma unroll
      for (int r = 0; r < 4; ++r) {
        float p0 = exp2f(z[mt][0][r] - SOFTMAX_OFF);
        float p1 = exp2f(z[mt][1][r] - SOFTMAX_OFF);
        float p2 = exp2f(z[mt][2][r] - SOFTMAX_OFF);
        float p3 = exp2f(z[mt][3][r] - SOFTMAX_OFF);
        if (masked) {
          if (s0 + c > qr + r) p0 = 0.f;
          if (s0 + 16 + c > qr + r) p1 = 0.f;
          if (s0 + 32 + c > qr + r) p2 = 0.f;
          if (s0 + 48 + c > qr + r) p3 = 0.f;
        }
        lsum[mt][r] += (p0 + p1) + (p2 + p3);
        u16* pr = &Ps[w][mt * 16 + g * 4 + r][c];
        pr[0] = f2bf(p0);
        pr[16] = f2bf(p1);
        pr[32] = f2bf(p2);
        pr[48] = f2bf(p3);
      }
    }

    // PV: V frags shared across both m-tiles (intra-wave LDS, no barrier)
#pragma unroll
    for (int kc = 0; kc < 2; ++kc) {
      short8 pf0 = *(const short8*)(&Ps[w][c][kc * 32 + g * 8]);
      short8 pf1 = *(const short8*)(&Ps[w][16 + c][kc * 32 + g * 8]);
#pragma unroll
      for (int nt = 0; nt < 4; ++nt) {
        short8 vf = *(const short8*)(&Vs[nt * 16 + c][kc * 32 + g * 8]);
        oacc[0][nt] = MFMA_BF16(pf0, vf, oacc[0][nt], 0, 0, 0);
        oacc[1][nt] = MFMA_BF16(pf1, vf, oacc[1][nt], 0, 0, 0);
      }
    }
  }

  // epilogue: reduce l across the 16 col-lanes, then O[b][t][h*64+d]
  int b = bh >> 4, h = bh & 15;
#pragma unroll
  for (int mt = 0; mt < 2; ++mt) {
#pragma unroll
    for (int r = 0; r < 4; ++r) {
      float l = lsum[mt][r];
      l += __shfl_xor(l, 1);
      l += __shfl_xor(l, 2);
      l += __shfl_xor(l, 4);
      l += __shfl_xor(l, 8);
      lsum[mt][r] = 1.f / l;
    }
#pragma unroll
    for (int nt = 0; nt < 4; ++nt)
#pragma unroll
      for (int r = 0; r < 4; ++r) {
        int trow = t0 + w * 32 + mt * 16 + g * 4 + r;
        float ov = oacc[mt][nt][r] * lsum[mt][r];
        O[((size_t)b * TT + trow) * CC + h * DH + nt * 16 + c] = f2bf(ov);
      }
  }
}

// ---------------------------------------------------------------------------
extern "C" void kernel_launch(void* const* d_in, const int* in_sizes, int n_in,
                              void* d_out, int out_size, void* d_ws,
                              size_t ws_size, hipStream_t stream) {
  const float* x = (const float*)d_in[0];
  const float* Wq = (const float*)d_in[1];
  const float* Wk = (const float*)d_in[2];
  const float* Wv = (const float*)d_in[3];
  const float* Wo = (const float*)d_in[4];
  const float* bo = (const float*)d_in[5];
  float* out = (float*)d_out;

  u16* ws = (u16*)d_ws;
  u16* xb = ws;                        // 8388608  (reused as Ow after QKV GEMM)
  u16* Wt = xb + 8388608;              // 3145728
  u16* Wob = Wt + 3145728;             // 1048576
  u16* qw = Wob + 1048576;             // 8388608
  u16* kw = qw + 8388608;              // 8388608
  u16* vw = kw + 8388608;              // 8388608 (transposed [bh][d][t])
  u16* Ow = xb;                        // alias: xb dead after gemm_bt<0>

  convert_kernel<<<12288, 256, 0, stream>>>(x, Wq, Wk, Wv, Wo, xb, Wt, Wob);

  gemm_bt<0><<<dim3(NQKV / 128, MM / 128), 256, 0, stream>>>(
      xb, Wt, MM, NQKV, CC, qw, kw, vw, nullptr, nullptr);

  flash_attn<<<dim3(TT / 128, BB * HH), 256, 0, stream>>>(qw, kw, vw, Ow);

  gemm_bt<1><<<dim3(CC / 128, MM / 128), 256, 0, stream>>>(
      Ow, Wob, MM, CC, CC, nullptr, nullptr, nullptr, out, bo);
}

// Round 6
// 322.767 us; speedup vs baseline: 1.1458x; 1.1458x over previous
//
#include <hip/hip_runtime.h>
#include <stdint.h>

typedef unsigned short u16;
typedef __attribute__((ext_vector_type(8))) short short8;
typedef __attribute__((ext_vector_type(4))) float floatx4;

#define MFMA_BF16 __builtin_amdgcn_mfma_f32_16x16x32_bf16

// dims
#define BB 4
#define TT 2048
#define CC 1024
#define HH 16
#define DH 64
#define MM (BB * TT)      // 8192
#define NQKV (3 * CC)     // 3072

// fixed softmax offset: 16 (e-domain) * log2(e), in exp2 domain
#define SOFTMAX_OFF 23.083120654223414f

__device__ __forceinline__ u16 f2bf(float f) {
  union { float f; uint32_t u; } un;
  un.f = f;
  uint32_t u = un.u;
  u += 0x7fffu + ((u >> 16) & 1u);   // round-to-nearest-even
  return (u16)(u >> 16);
}

__device__ __forceinline__ uint32_t pk2(float a, float b) {
  return (uint32_t)f2bf(a) | ((uint32_t)f2bf(b) << 16);
}

// async global->LDS, 16B per lane. lds dst = wave-uniform base + lane*16.
__device__ __forceinline__ void gload_lds16(const u16* g, u16* l) {
  __builtin_amdgcn_global_load_lds(
      (const __attribute__((address_space(1))) unsigned int*)g,
      (__attribute__((address_space(3))) unsigned int*)l, 16, 0, 0);
}

// ---------------------------------------------------------------------------
// Kernel 0: fp32 -> bf16 conversions + coalesced weight transpose.
// ---------------------------------------------------------------------------
__global__ __launch_bounds__(256) void convert_kernel(
    const float* __restrict__ x, const float* __restrict__ Wq,
    const float* __restrict__ Wk, const float* __restrict__ Wv,
    const float* __restrict__ Wo, u16* __restrict__ xb,
    u16* __restrict__ Wt, u16* __restrict__ Wob) {
  __shared__ float T[32][33];
  int bid = blockIdx.x, tid = threadIdx.x;
  if (bid < 8192) {
    int i = (bid * 256 + tid) * 4;
    float4 f = *(const float4*)(x + i);
    uint2 o = {pk2(f.x, f.y), pk2(f.z, f.w)};
    *(uint2*)(xb + i) = o;
  } else if (bid < 8192 + 3072) {
    int tb = bid - 8192;
    int sec = tb >> 10, rem = tb & 1023;
    int h = rem >> 6, sub = rem & 63, ct = sub >> 1, dt = sub & 1;
    const float* W = (sec == 0) ? Wq : (sec == 1) ? Wk : Wv;
    int tx = tid & 31, ty = tid >> 5;
#pragma unroll
    for (int p = 0; p < 4; ++p)
      T[ty + 8 * p][tx] =
          W[((size_t)h * CC + ct * 32 + ty + 8 * p) * DH + dt * 32 + tx];
    __syncthreads();
#pragma unroll
    for (int p = 0; p < 4; ++p) {
      int n = sec * 1024 + h * 64 + dt * 32 + ty + 8 * p;
      Wt[(size_t)n * CC + ct * 32 + tx] = f2bf(T[tx][ty + 8 * p]);
    }
  } else {
    int i = ((bid - 11264) * 256 + tid) * 4;
    float4 f = *(const float4*)(Wo + i);
    uint2 o = {pk2(f.x, f.y), pk2(f.z, f.w)};
    *(uint2*)(Wob + i) = o;
  }
}

// ---------------------------------------------------------------------------
// GEMM: C[M,N] = A[M,K] @ Bt[N,K]^T, bf16 in, fp32 accum. m97 pattern.
// MODE 0: q (scaled) / k / v all coalesced [bh][t][d]. MODE 1: +bias fp32.
// ---------------------------------------------------------------------------
template <int MODE>
__global__ __launch_bounds__(256) void gemm_bt(
    const u16* __restrict__ A, const u16* __restrict__ Bt, int M, int N, int K,
    u16* __restrict__ qout, u16* __restrict__ kout, u16* __restrict__ vout,
    float* __restrict__ out, const float* __restrict__ bias) {
  __shared__ u16 As[128][64];  // unpadded: required by global_load_lds
  __shared__ u16 Bs[128][64];
  int tid = threadIdx.x;
  int lane = tid & 63, w = tid >> 6;
  int wm = w >> 1, wn = w & 1;
  int g = lane >> 4, c = lane & 15;
  int m0 = blockIdx.y * 128, n0 = blockIdx.x * 128;

  floatx4 acc[4][4];
#pragma unroll
  for (int i = 0; i < 4; ++i)
#pragma unroll
    for (int j = 0; j < 4; ++j) acc[i][j] = (floatx4){0.f, 0.f, 0.f, 0.f};

  int srow = 32 * w + (lane >> 3);
  int scol = (lane & 7) * 8;
  const u16* Ag = A + (size_t)(m0 + srow) * K + scol;
  const u16* Bg = Bt + (size_t)(n0 + srow) * K + scol;
  u16* AsB = &As[32 * w][0];
  u16* BsB = &Bs[32 * w][0];

  for (int k0 = 0; k0 < K; k0 += 64) {
    __syncthreads();
#pragma unroll
    for (int j = 0; j < 4; ++j)
      gload_lds16(Ag + k0 + (size_t)j * 8 * K, AsB + j * 512);
#pragma unroll
    for (int j = 0; j < 4; ++j)
      gload_lds16(Bg + k0 + (size_t)j * 8 * K, BsB + j * 512);
    __syncthreads();
#pragma unroll
    for (int kc = 0; kc < 2; ++kc) {
      short8 af[4], bfv[4];
#pragma unroll
      for (int mt = 0; mt < 4; ++mt)
        af[mt] = *(const short8*)(&As[wm * 64 + mt * 16 + c][kc * 32 + g * 8]);
#pragma unroll
      for (int nt = 0; nt < 4; ++nt)
        bfv[nt] = *(const short8*)(&Bs[wn * 64 + nt * 16 + c][kc * 32 + g * 8]);
#pragma unroll
      for (int mt = 0; mt < 4; ++mt)
#pragma unroll
        for (int nt = 0; nt < 4; ++nt)
          acc[mt][nt] = MFMA_BF16(af[mt], bfv[nt], acc[mt][nt], 0, 0, 0);
    }
  }

#pragma unroll
  for (int mt = 0; mt < 4; ++mt) {
#pragma unroll
    for (int nt = 0; nt < 4; ++nt) {
#pragma unroll
      for (int r = 0; r < 4; ++r) {
        int m = m0 + wm * 64 + mt * 16 + g * 4 + r;  // C-layout: row=(lane>>4)*4+reg
        int n = n0 + wn * 64 + nt * 16 + c;          //           col=lane&15
        float v = acc[mt][nt][r];
        if (MODE == 0) {
          int b = m >> 11, t = m & 2047;
          int sec = n >> 10, h = (n >> 6) & 15, d = n & 63;
          size_t idx = (((size_t)(b * HH + h)) * TT + t) * DH + d;
          if (sec == 0)
            qout[idx] = f2bf(v * 0.18033688011112042f);
          // ^ DH^-0.5 * log2(e): softmax runs in exp2 domain
          else if (sec == 1)
            kout[idx] = f2bf(v);
          else
            vout[idx] = f2bf(v);  // coalesced; flash transposes in LDS
        } else {
          out[(size_t)m * N + n] = v + bias[n];
        }
      }
    }
  }
}

// ---------------------------------------------------------------------------
// Flash attention (causal), fixed-max softmax. 256 thr = 4 waves; wave w owns
// Q rows [t0+32w, t0+32w+32) as 2 m-tiles. 64-key tiles, K+V register-
// double-buffered into LDS (latency hidden behind compute). V transposed
// during LDS staging. K/V fragments shared across both m-tiles.
// ---------------------------------------------------------------------------
__global__ __launch_bounds__(256, 4) void flash_attn(
    const u16* __restrict__ q, const u16* __restrict__ k,
    const u16* __restrict__ v, u16* __restrict__ O) {
  __shared__ u16 Ks[64][72];     // [s][d]
  __shared__ u16 Vs[64][72];     // [d][s] (transposed at staging)
  __shared__ u16 Ps[4][32][72];  // per-wave P tile [m 0..31][s]

  int tid = threadIdx.x;
  int lane = tid & 63, w = tid >> 6;
  int g = lane >> 4, c = lane & 15;

  // balance swizzle: alternate heavy/light direction per 256-block group
  int id = blockIdx.y * 16 + blockIdx.x;
  int bh = id >> 4;
  int x = id & 15;
  int t0 = (((id >> 8) & 1) ? x : 15 - x) * 128;

  const u16* qb = q + (size_t)bh * TT * DH;
  const u16* kb = k + (size_t)bh * TT * DH;
  const u16* vb = v + (size_t)bh * TT * DH;

  // Q fragments persistent in registers (A-layout: m=lane&15, k=(lane>>4)*8+j)
  short8 qf[2][2];
#pragma unroll
  for (int mt = 0; mt < 2; ++mt) {
    int qrow = t0 + w * 32 + mt * 16 + c;
#pragma unroll
    for (int kc = 0; kc < 2; ++kc)
      qf[mt][kc] = *(const short8*)(qb + (size_t)qrow * DH + kc * 32 + g * 8);
  }

  floatx4 oacc[2][4];
#pragma unroll
  for (int mt = 0; mt < 2; ++mt)
#pragma unroll
    for (int nt = 0; nt < 4; ++nt) oacc[mt][nt] = (floatx4){0.f, 0.f, 0.f, 0.f};
  float lsum[2][4];
#pragma unroll
  for (int mt = 0; mt < 2; ++mt)
#pragma unroll
    for (int r = 0; r < 4; ++r) lsum[mt][r] = 0.f;

  // staging: row = tid>>2 (0..63), col base = (tid&3)*16, 2x16B per tensor
  int srow = tid >> 2, scol = (tid & 3) * 16;
  const u16* kbase = kb + (size_t)srow * DH + scol;
  const u16* vbase = vb + (size_t)srow * DH + scol;

  // preload iter 0
  uint4 kr0 = *(const uint4*)(kbase);
  uint4 kr1 = *(const uint4*)(kbase + 8);
  uint4 vr0 = *(const uint4*)(vbase);
  uint4 vr1 = *(const uint4*)(vbase + 8);

  int niter = (t0 >> 6) + 2;
  int nfull = t0 >> 6;  // iterations needing no causal mask
  int wmax = t0 + w * 32 + 31;
  for (int it = 0; it < niter; ++it) {
    int s0 = it << 6;
    __syncthreads();  // all waves done reading prev tiles
    *(uint4*)(&Ks[srow][scol]) = kr0;
    *(uint4*)(&Ks[srow][scol + 8]) = kr1;
    {  // V transpose: lane holds V[s=srow][d=scol..scol+15] -> Vs[d][s]
      const u16* pv0 = (const u16*)&vr0;
      const u16* pv1 = (const u16*)&vr1;
#pragma unroll
      for (int j = 0; j < 8; ++j) {
        Vs[scol + j][srow] = pv0[j];
        Vs[scol + 8 + j][srow] = pv1[j];
      }
    }
    __syncthreads();
    if (it + 1 < niter) {  // prefetch next tile: latency hidden by compute
      size_t off = (size_t)((it + 1) << 6) * DH;
      kr0 = *(const uint4*)(kbase + off);
      kr1 = *(const uint4*)(kbase + off + 8);
      vr0 = *(const uint4*)(vbase + off);
      vr1 = *(const uint4*)(vbase + off + 8);
    }
    if (s0 > wmax) continue;  // wave-uniform: tile fully masked (last iter)
    bool masked = (it >= nfull);

    // S = Q K^T ; kf shared across both m-tiles
    floatx4 z[2][4];
#pragma unroll
    for (int mt = 0; mt < 2; ++mt)
#pragma unroll
      for (int n = 0; n < 4; ++n) z[mt][n] = (floatx4){0.f, 0.f, 0.f, 0.f};
#pragma unroll
    for (int kc = 0; kc < 2; ++kc)
#pragma unroll
      for (int n = 0; n < 4; ++n) {
        short8 kf = *(const short8*)(&Ks[n * 16 + c][kc * 32 + g * 8]);
        z[0][n] = MFMA_BF16(qf[0][kc], kf, z[0][n], 0, 0, 0);
        z[1][n] = MFMA_BF16(qf[1][kc], kf, z[1][n], 0, 0, 0);
      }

    // fixed-max softmax, inlined per row; write P to per-wave LDS
#pragma unroll
    for (int mt = 0; mt < 2; ++mt) {
      int qr = t0 + w * 32 + mt * 16 + g * 4;
#pragma unroll
      for (int r = 0; r < 4; ++r) {
        float p0 = exp2f(z[mt][0][r] - SOFTMAX_OFF);
        float p1 = exp2f(z[mt][1][r] - SOFTMAX_OFF);
        float p2 = exp2f(z[mt][2][r] - SOFTMAX_OFF);
        float p3 = exp2f(z[mt][3][r] - SOFTMAX_OFF);
        if (masked) {
          if (s0 + c > qr + r) p0 = 0.f;
          if (s0 + 16 + c > qr + r) p1 = 0.f;
          if (s0 + 32 + c > qr + r) p2 = 0.f;
          if (s0 + 48 + c > qr + r) p3 = 0.f;
        }
        lsum[mt][r] += (p0 + p1) + (p2 + p3);
        u16* pr = &Ps[w][mt * 16 + g * 4 + r][c];
        pr[0] = f2bf(p0);
        pr[16] = f2bf(p1);
        pr[32] = f2bf(p2);
        pr[48] = f2bf(p3);
      }
    }

    // PV: vf shared across both m-tiles (intra-wave LDS, no barrier)
#pragma unroll
    for (int kc = 0; kc < 2; ++kc) {
      short8 pf0 = *(const short8*)(&Ps[w][c][kc * 32 + g * 8]);
      short8 pf1 = *(const short8*)(&Ps[w][16 + c][kc * 32 + g * 8]);
#pragma unroll
      for (int nt = 0; nt < 4; ++nt) {
        short8 vf = *(const short8*)(&Vs[nt * 16 + c][kc * 32 + g * 8]);
        oacc[0][nt] = MFMA_BF16(pf0, vf, oacc[0][nt], 0, 0, 0);
        oacc[1][nt] = MFMA_BF16(pf1, vf, oacc[1][nt], 0, 0, 0);
      }
    }
  }

  // epilogue: reduce l across the 16 col-lanes, then O[b][t][h*64+d]
  int b = bh >> 4, h = bh & 15;
#pragma unroll
  for (int mt = 0; mt < 2; ++mt) {
#pragma unroll
    for (int r = 0; r < 4; ++r) {
      float l = lsum[mt][r];
      l += __shfl_xor(l, 1);
      l += __shfl_xor(l, 2);
      l += __shfl_xor(l, 4);
      l += __shfl_xor(l, 8);
      lsum[mt][r] = 1.f / l;
    }
#pragma unroll
    for (int nt = 0; nt < 4; ++nt)
#pragma unroll
      for (int r = 0; r < 4; ++r) {
        int trow = t0 + w * 32 + mt * 16 + g * 4 + r;
        float ov = oacc[mt][nt][r] * lsum[mt][r];
        O[((size_t)b * TT + trow) * CC + h * DH + nt * 16 + c] = f2bf(ov);
      }
  }
}

// ---------------------------------------------------------------------------
extern "C" void kernel_launch(void* const* d_in, const int* in_sizes, int n_in,
                              void* d_out, int out_size, void* d_ws,
                              size_t ws_size, hipStream_t stream) {
  const float* x = (const float*)d_in[0];
  const float* Wq = (const float*)d_in[1];
  const float* Wk = (const float*)d_in[2];
  const float* Wv = (const float*)d_in[3];
  const float* Wo = (const float*)d_in[4];
  const float* bo = (const float*)d_in[5];
  float* out = (float*)d_out;

  u16* ws = (u16*)d_ws;
  u16* xb = ws;                        // 8388608  (reused as Ow after QKV GEMM)
  u16* Wt = xb + 8388608;              // 3145728
  u16* Wob = Wt + 3145728;             // 1048576
  u16* qw = Wob + 1048576;             // 8388608
  u16* kw = qw + 8388608;              // 8388608
  u16* vw = kw + 8388608;              // 8388608 ([bh][t][d], coalesced)
  u16* Ow = xb;                        // alias: xb dead after gemm_bt<0>

  convert_kernel<<<12288, 256, 0, stream>>>(x, Wq, Wk, Wv, Wo, xb, Wt, Wob);

  gemm_bt<0><<<dim3(NQKV / 128, MM / 128), 256, 0, stream>>>(
      xb, Wt, MM, NQKV, CC, qw, kw, vw, nullptr, nullptr);

  flash_attn<<<dim3(TT / 128, BB * HH), 256, 0, stream>>>(qw, kw, vw, Ow);

  gemm_bt<1><<<dim3(CC / 128, MM / 128), 256, 0, stream>>>(
      Ow, Wob, MM, CC, CC, nullptr, nullptr, nullptr, out, bo);
}

// Round 7
// 314.157 us; speedup vs baseline: 1.1772x; 1.0274x over previous
//
#include <hip/hip_runtime.h>
#include <stdint.h>

typedef unsigned short u16;
typedef __attribute__((ext_vector_type(8))) short short8;
typedef __attribute__((ext_vector_type(4))) float floatx4;

#define MFMA_BF16 __builtin_amdgcn_mfma_f32_16x16x32_bf16

// dims
#define BB 4
#define TT 2048
#define CC 1024
#define HH 16
#define DH 64
#define MM (BB * TT)      // 8192
#define NQKV (3 * CC)     // 3072

// fixed softmax offset: 16 (e-domain) * log2(e), in exp2 domain
#define SOFTMAX_OFF 23.083120654223414f

__device__ __forceinline__ u16 f2bf(float f) {
  union { float f; uint32_t u; } un;
  un.f = f;
  uint32_t u = un.u;
  u += 0x7fffu + ((u >> 16) & 1u);   // round-to-nearest-even
  return (u16)(u >> 16);
}

__device__ __forceinline__ uint32_t pk2(float a, float b) {
  return (uint32_t)f2bf(a) | ((uint32_t)f2bf(b) << 16);
}

// pack hi16(a) | hi16(b)<<16 in ONE v_perm_b32 (truncating bf16 round)
__device__ __forceinline__ uint32_t pktrunc(float a, float b) {
  union { float f; uint32_t u; } ua, ub;
  ua.f = a; ub.f = b;
  return __builtin_amdgcn_perm(ub.u, ua.u, 0x07060302u);
}

// async global->LDS, 16B per lane. lds dst = wave-uniform base + lane*16.
__device__ __forceinline__ void gload_lds16(const u16* g, u16* l) {
  __builtin_amdgcn_global_load_lds(
      (const __attribute__((address_space(1))) unsigned int*)g,
      (__attribute__((address_space(3))) unsigned int*)l, 16, 0, 0);
}

// ---------------------------------------------------------------------------
// Kernel 0: fp32 -> bf16 conversions + coalesced weight transpose.
// ---------------------------------------------------------------------------
__global__ __launch_bounds__(256) void convert_kernel(
    const float* __restrict__ x, const float* __restrict__ Wq,
    const float* __restrict__ Wk, const float* __restrict__ Wv,
    const float* __restrict__ Wo, u16* __restrict__ xb,
    u16* __restrict__ Wt, u16* __restrict__ Wob) {
  __shared__ float T[32][33];
  int bid = blockIdx.x, tid = threadIdx.x;
  if (bid < 8192) {
    int i = (bid * 256 + tid) * 4;
    float4 f = *(const float4*)(x + i);
    uint2 o = {pk2(f.x, f.y), pk2(f.z, f.w)};
    *(uint2*)(xb + i) = o;
  } else if (bid < 8192 + 3072) {
    int tb = bid - 8192;
    int sec = tb >> 10, rem = tb & 1023;
    int h = rem >> 6, sub = rem & 63, ct = sub >> 1, dt = sub & 1;
    const float* W = (sec == 0) ? Wq : (sec == 1) ? Wk : Wv;
    int tx = tid & 31, ty = tid >> 5;
#pragma unroll
    for (int p = 0; p < 4; ++p)
      T[ty + 8 * p][tx] =
          W[((size_t)h * CC + ct * 32 + ty + 8 * p) * DH + dt * 32 + tx];
    __syncthreads();
#pragma unroll
    for (int p = 0; p < 4; ++p) {
      int n = sec * 1024 + h * 64 + dt * 32 + ty + 8 * p;
      Wt[(size_t)n * CC + ct * 32 + tx] = f2bf(T[tx][ty + 8 * p]);
    }
  } else {
    int i = ((bid - 11264) * 256 + tid) * 4;
    float4 f = *(const float4*)(Wo + i);
    uint2 o = {pk2(f.x, f.y), pk2(f.z, f.w)};
    *(uint2*)(Wob + i) = o;
  }
}

// ---------------------------------------------------------------------------
// GEMM: C[M,N] = A[M,K] @ Bt[N,K]^T, bf16 in, fp32 accum. m97 pattern.
// MODE 0: q (scaled) / k / v all coalesced [bh][t][d]. MODE 1: +bias fp32.
// ---------------------------------------------------------------------------
template <int MODE>
__global__ __launch_bounds__(256) void gemm_bt(
    const u16* __restrict__ A, const u16* __restrict__ Bt, int M, int N, int K,
    u16* __restrict__ qout, u16* __restrict__ kout, u16* __restrict__ vout,
    float* __restrict__ out, const float* __restrict__ bias) {
  __shared__ u16 As[128][64];  // unpadded: required by global_load_lds
  __shared__ u16 Bs[128][64];
  int tid = threadIdx.x;
  int lane = tid & 63, w = tid >> 6;
  int wm = w >> 1, wn = w & 1;
  int g = lane >> 4, c = lane & 15;
  int m0 = blockIdx.y * 128, n0 = blockIdx.x * 128;

  floatx4 acc[4][4];
#pragma unroll
  for (int i = 0; i < 4; ++i)
#pragma unroll
    for (int j = 0; j < 4; ++j) acc[i][j] = (floatx4){0.f, 0.f, 0.f, 0.f};

  int srow = 32 * w + (lane >> 3);
  int scol = (lane & 7) * 8;
  const u16* Ag = A + (size_t)(m0 + srow) * K + scol;
  const u16* Bg = Bt + (size_t)(n0 + srow) * K + scol;
  u16* AsB = &As[32 * w][0];
  u16* BsB = &Bs[32 * w][0];

  for (int k0 = 0; k0 < K; k0 += 64) {
    __syncthreads();
#pragma unroll
    for (int j = 0; j < 4; ++j)
      gload_lds16(Ag + k0 + (size_t)j * 8 * K, AsB + j * 512);
#pragma unroll
    for (int j = 0; j < 4; ++j)
      gload_lds16(Bg + k0 + (size_t)j * 8 * K, BsB + j * 512);
    __syncthreads();
#pragma unroll
    for (int kc = 0; kc < 2; ++kc) {
      short8 af[4], bfv[4];
#pragma unroll
      for (int mt = 0; mt < 4; ++mt)
        af[mt] = *(const short8*)(&As[wm * 64 + mt * 16 + c][kc * 32 + g * 8]);
#pragma unroll
      for (int nt = 0; nt < 4; ++nt)
        bfv[nt] = *(const short8*)(&Bs[wn * 64 + nt * 16 + c][kc * 32 + g * 8]);
#pragma unroll
      for (int mt = 0; mt < 4; ++mt)
#pragma unroll
        for (int nt = 0; nt < 4; ++nt)
          acc[mt][nt] = MFMA_BF16(af[mt], bfv[nt], acc[mt][nt], 0, 0, 0);
    }
  }

#pragma unroll
  for (int mt = 0; mt < 4; ++mt) {
#pragma unroll
    for (int nt = 0; nt < 4; ++nt) {
#pragma unroll
      for (int r = 0; r < 4; ++r) {
        int m = m0 + wm * 64 + mt * 16 + g * 4 + r;  // C-layout: row=(lane>>4)*4+reg
        int n = n0 + wn * 64 + nt * 16 + c;          //           col=lane&15
        float v = acc[mt][nt][r];
        if (MODE == 0) {
          int b = m >> 11, t = m & 2047;
          int sec = n >> 10, h = (n >> 6) & 15, d = n & 63;
          size_t idx = (((size_t)(b * HH + h)) * TT + t) * DH + d;
          if (sec == 0)
            qout[idx] = f2bf(v * 0.18033688011112042f);
          // ^ DH^-0.5 * log2(e): softmax runs in exp2 domain
          else if (sec == 1)
            kout[idx] = f2bf(v);
          else
            vout[idx] = f2bf(v);  // coalesced; vtrans permutes afterwards
        } else {
          out[(size_t)m * N + n] = v + bias[n];
        }
      }
    }
  }
}

// ---------------------------------------------------------------------------
// V permute-transpose: v[bh][s][d] -> vP[bh][d][tile][u] where
// s = tile*64 + (u&3)*16 + (u>>2)  (i.e. u = 4*(s&15) + ((s>>4)&3)).
// This u-order makes flash's P-row writes contiguous (b64) while keeping
// the PV MFMA contraction consistent (same sigma on both operands).
// ---------------------------------------------------------------------------
__global__ __launch_bounds__(256) void vtrans(const u16* __restrict__ v,
                                              u16* __restrict__ vP) {
  __shared__ u16 Ld[64][72];
  int tile = blockIdx.x, bh = blockIdx.y, tid = threadIdx.x;
  int row = tid >> 2, col = (tid & 3) * 16;
  const u16* src = v + ((size_t)bh * TT + tile * 64 + row) * DH + col;
  *(uint4*)(&Ld[row][col]) = *(const uint4*)(src);
  *(uint4*)(&Ld[row][col + 8]) = *(const uint4*)(src + 8);
  __syncthreads();
  int d = tid >> 2, u0 = (tid & 3) * 16;
  union { u16 h[16]; uint4 q[2]; } o;
#pragma unroll
  for (int k = 0; k < 16; ++k) {
    int u = u0 + k;
    int s = ((u & 3) << 4) | (u >> 2);
    o.h[k] = Ld[s][d];
  }
  u16* dst = vP + ((size_t)(bh * DH + d)) * TT + tile * 64 + u0;
  *(uint4*)(dst) = o.q[0];
  *(uint4*)(dst + 8) = o.q[1];
}

// ---------------------------------------------------------------------------
// Flash attention (causal), fixed-max softmax, permuted-s PV path.
// 256 thr = 4 waves; wave w owns Q rows [t0+32w, t0+32w+32) as 2 m-tiles.
// 64-key tiles, K+vP register-double-buffered into LDS. P written as packed
// b64 (v_perm truncation). K/V fragments shared across both m-tiles.
// ---------------------------------------------------------------------------
__global__ __launch_bounds__(256, 4) void flash_attn(
    const u16* __restrict__ q, const u16* __restrict__ k,
    const u16* __restrict__ vP, u16* __restrict__ O) {
  __shared__ u16 Ks[64][72];     // [s][d]
  __shared__ u16 Vs[64][72];     // [d][u]  (u = permuted s)
  __shared__ u16 Ps[4][32][72];  // per-wave P tile [m][u]

  int tid = threadIdx.x;
  int lane = tid & 63, w = tid >> 6;
  int g = lane >> 4, c = lane & 15;

  // balance swizzle: alternate heavy/light direction per 256-block group
  int id = blockIdx.y * 16 + blockIdx.x;
  int bh = id >> 4;
  int x = id & 15;
  int t0 = (((id >> 8) & 1) ? x : 15 - x) * 128;

  const u16* qb = q + (size_t)bh * TT * DH;
  const u16* kb = k + (size_t)bh * TT * DH;
  const u16* vb = vP + (size_t)bh * DH * TT;

  // Q fragments persistent in registers (A-layout: m=lane&15, k=(lane>>4)*8+j)
  short8 qf[2][2];
#pragma unroll
  for (int mt = 0; mt < 2; ++mt) {
    int qrow = t0 + w * 32 + mt * 16 + c;
#pragma unroll
    for (int kc = 0; kc < 2; ++kc)
      qf[mt][kc] = *(const short8*)(qb + (size_t)qrow * DH + kc * 32 + g * 8);
  }

  floatx4 oacc[2][4];
#pragma unroll
  for (int mt = 0; mt < 2; ++mt)
#pragma unroll
    for (int nt = 0; nt < 4; ++nt) oacc[mt][nt] = (floatx4){0.f, 0.f, 0.f, 0.f};
  float lsum[2][4];
#pragma unroll
  for (int mt = 0; mt < 2; ++mt)
#pragma unroll
    for (int r = 0; r < 4; ++r) lsum[mt][r] = 0.f;

  // staging: row = tid>>2 (0..63), col base = (tid&3)*16, 2x16B per tensor
  int srow = tid >> 2, scol = (tid & 3) * 16;
  const u16* kbase = kb + (size_t)srow * DH + scol;
  const u16* vbase = vb + (size_t)srow * TT + scol;  // vP rows: [d][t-contig]

  // preload iter 0
  uint4 kr0 = *(const uint4*)(kbase);
  uint4 kr1 = *(const uint4*)(kbase + 8);
  uint4 vr0 = *(const uint4*)(vbase);
  uint4 vr1 = *(const uint4*)(vbase + 8);

  int niter = (t0 >> 6) + 2;
  int nfull = t0 >> 6;  // iterations needing no causal mask
  int wmax = t0 + w * 32 + 31;
  for (int it = 0; it < niter; ++it) {
    int s0 = it << 6;
    __syncthreads();  // all waves done reading prev tiles
    *(uint4*)(&Ks[srow][scol]) = kr0;
    *(uint4*)(&Ks[srow][scol + 8]) = kr1;
    *(uint4*)(&Vs[srow][scol]) = vr0;
    *(uint4*)(&Vs[srow][scol + 8]) = vr1;
    __syncthreads();
    if (it + 1 < niter) {  // prefetch next tile: latency hidden by compute
      size_t koff = (size_t)((it + 1) << 6) * DH;
      int voff = (it + 1) << 6;
      kr0 = *(const uint4*)(kbase + koff);
      kr1 = *(const uint4*)(kbase + koff + 8);
      vr0 = *(const uint4*)(vbase + voff);
      vr1 = *(const uint4*)(vbase + voff + 8);
    }
    if (s0 > wmax) continue;  // wave-uniform: tile fully masked (last iter)
    bool masked = (it >= nfull);

    // S = Q K^T ; kf shared across both m-tiles
    floatx4 z[2][4];
#pragma unroll
    for (int mt = 0; mt < 2; ++mt)
#pragma unroll
      for (int n = 0; n < 4; ++n) z[mt][n] = (floatx4){0.f, 0.f, 0.f, 0.f};
#pragma unroll
    for (int kc = 0; kc < 2; ++kc)
#pragma unroll
      for (int n = 0; n < 4; ++n) {
        short8 kf = *(const short8*)(&Ks[n * 16 + c][kc * 32 + g * 8]);
        z[0][n] = MFMA_BF16(qf[0][kc], kf, z[0][n], 0, 0, 0);
        z[1][n] = MFMA_BF16(qf[1][kc], kf, z[1][n], 0, 0, 0);
      }

    // fixed-max softmax; P packed to bf16 by v_perm truncation, b64 stores
#pragma unroll
    for (int mt = 0; mt < 2; ++mt) {
      int qr = t0 + w * 32 + mt * 16 + g * 4;
#pragma unroll
      for (int r = 0; r < 4; ++r) {
        float p0 = exp2f(z[mt][0][r] - SOFTMAX_OFF);
        float p1 = exp2f(z[mt][1][r] - SOFTMAX_OFF);
        float p2 = exp2f(z[mt][2][r] - SOFTMAX_OFF);
        float p3 = exp2f(z[mt][3][r] - SOFTMAX_OFF);
        if (masked) {
          if (s0 + c > qr + r) p0 = 0.f;
          if (s0 + 16 + c > qr + r) p1 = 0.f;
          if (s0 + 32 + c > qr + r) p2 = 0.f;
          if (s0 + 48 + c > qr + r) p3 = 0.f;
        }
        lsum[mt][r] += (p0 + p1) + (p2 + p3);
        // u-layout: s = n*16+c -> u = 4c+n; 4 values contiguous at u0=4c
        uint2 pk = {pktrunc(p0, p1), pktrunc(p2, p3)};
        *(uint2*)(&Ps[w][mt * 16 + g * 4 + r][4 * c]) = pk;
      }
    }

    // PV: vf shared across both m-tiles (intra-wave LDS, no barrier)
#pragma unroll
    for (int kc = 0; kc < 2; ++kc) {
      short8 pf0 = *(const short8*)(&Ps[w][c][kc * 32 + g * 8]);
      short8 pf1 = *(const short8*)(&Ps[w][16 + c][kc * 32 + g * 8]);
#pragma unroll
      for (int nt = 0; nt < 4; ++nt) {
        short8 vf = *(const short8*)(&Vs[nt * 16 + c][kc * 32 + g * 8]);
        oacc[0][nt] = MFMA_BF16(pf0, vf, oacc[0][nt], 0, 0, 0);
        oacc[1][nt] = MFMA_BF16(pf1, vf, oacc[1][nt], 0, 0, 0);
      }
    }
  }

  // epilogue: reduce l across the 16 col-lanes, then O[b][t][h*64+d]
  int b = bh >> 4, h = bh & 15;
#pragma unroll
  for (int mt = 0; mt < 2; ++mt) {
#pragma unroll
    for (int r = 0; r < 4; ++r) {
      float l = lsum[mt][r];
      l += __shfl_xor(l, 1);
      l += __shfl_xor(l, 2);
      l += __shfl_xor(l, 4);
      l += __shfl_xor(l, 8);
      lsum[mt][r] = 1.f / l;
    }
#pragma unroll
    for (int nt = 0; nt < 4; ++nt)
#pragma unroll
      for (int r = 0; r < 4; ++r) {
        int trow = t0 + w * 32 + mt * 16 + g * 4 + r;
        float ov = oacc[mt][nt][r] * lsum[mt][r];
        O[((size_t)b * TT + trow) * CC + h * DH + nt * 16 + c] = f2bf(ov);
      }
  }
}

// ---------------------------------------------------------------------------
extern "C" void kernel_launch(void* const* d_in, const int* in_sizes, int n_in,
                              void* d_out, int out_size, void* d_ws,
                              size_t ws_size, hipStream_t stream) {
  const float* x = (const float*)d_in[0];
  const float* Wq = (const float*)d_in[1];
  const float* Wk = (const float*)d_in[2];
  const float* Wv = (const float*)d_in[3];
  const float* Wo = (const float*)d_in[4];
  const float* bo = (const float*)d_in[5];
  float* out = (float*)d_out;

  u16* ws = (u16*)d_ws;
  u16* xb = ws;                        // 8388608  (reused as Ow after QKV GEMM)
  u16* Wt = xb + 8388608;              // 3145728
  u16* Wob = Wt + 3145728;             // 1048576
  u16* qw = Wob + 1048576;             // 8388608
  u16* kw = qw + 8388608;              // 8388608
  u16* vw = kw + 8388608;              // 8388608 ([bh][t][d], coalesced)
  u16* vP = vw + 8388608;              // 8388608 (permuted [bh][d][tile][u])
  u16* Ow = xb;                        // alias: xb dead after gemm_bt<0>

  convert_kernel<<<12288, 256, 0, stream>>>(x, Wq, Wk, Wv, Wo, xb, Wt, Wob);

  gemm_bt<0><<<dim3(NQKV / 128, MM / 128), 256, 0, stream>>>(
      xb, Wt, MM, NQKV, CC, qw, kw, vw, nullptr, nullptr);

  vtrans<<<dim3(TT / 64, BB * HH), 256, 0, stream>>>(vw, vP);

  flash_attn<<<dim3(TT / 128, BB * HH), 256, 0, stream>>>(qw, kw, vP, Ow);

  gemm_bt<1><<<dim3(CC / 128, MM / 128), 256, 0, stream>>>(
      Ow, Wob, MM, CC, CC, nullptr, nullptr, nullptr, out, bo);
}